// Round 2
// baseline (366.355 us; speedup 1.0000x reference)
//
#include <hip/hip_runtime.h>
#include <hip/hip_bf16.h>

#define D 512
#define D4 (D / 4)
#define ND 4
#define EPSF 1e-3f

// ---------------------------------------------------------------------------
// Kernel A: per-row domain id (argmax of one-hot, first-max-wins) + counts.
// ---------------------------------------------------------------------------
__global__ __launch_bounds__(256) void dom_kernel(const float4* __restrict__ ind,
                                                  unsigned char* __restrict__ dom,
                                                  float* __restrict__ cnt, int B) {
  __shared__ int lc[ND];
  const int t = threadIdx.x;
  if (t < ND) lc[t] = 0;
  __syncthreads();
  const int i = blockIdx.x * blockDim.x + t;
  if (i < B) {
    float4 v = ind[i];  // fully coalesced: thread i reads floats [4i, 4i+4)
    int d = 0;
    float best = v.x;
    if (v.y > best) { best = v.y; d = 1; }
    if (v.z > best) { best = v.z; d = 2; }
    if (v.w > best) { best = v.w; d = 3; }
    dom[i] = (unsigned char)d;
    atomicAdd(&lc[d], 1);
  }
  __syncthreads();
  if (t < ND && lc[t]) atomicAdd(&cnt[t], (float)lc[t]);
}

// ---------------------------------------------------------------------------
// Kernel B: per-domain per-column sum & sqsum.
// Layout: 256 thr/block; thread owns cols [tc*4, tc*4+4), row-group rg=t>>7.
// Register accumulators with STATIC indexing (uniform-per-wave branch on dom;
// runtime-indexed register arrays would spill to scratch).
// ---------------------------------------------------------------------------
__global__ __launch_bounds__(256) void stats_kernel(const float4* __restrict__ x,
                                                    const unsigned char* __restrict__ dom,
                                                    float* __restrict__ sums,
                                                    float* __restrict__ sqs,
                                                    int B, int rowsPerBlock) {
  const int t = threadIdx.x;
  const int tc = t & 127;
  const int rg = t >> 7;
  const int base = blockIdx.x * rowsPerBlock;
  float s[ND][4] = {};
  float q[ND][4] = {};
  for (int it = 0; it < rowsPerBlock; it += 2) {
    const int r = base + it + rg;
    if (r >= B) break;
    const int d = dom[r];  // same addr across wave -> broadcast
    float4 v = x[(size_t)r * D4 + tc];
#pragma unroll
    for (int dd = 0; dd < ND; ++dd) {
      if (d == dd) {  // wave-uniform branch (whole wave shares the row)
        s[dd][0] += v.x; s[dd][1] += v.y; s[dd][2] += v.z; s[dd][3] += v.w;
        q[dd][0] += v.x * v.x; q[dd][1] += v.y * v.y;
        q[dd][2] += v.z * v.z; q[dd][3] += v.w * v.w;
      }
    }
  }
  // Reduce the two row-groups through LDS, then one atomicAdd per value.
  __shared__ float red[128 * 32];  // 16 KiB
  if (rg) {
#pragma unroll
    for (int dd = 0; dd < ND; ++dd)
#pragma unroll
      for (int c = 0; c < 4; ++c) {
        red[tc * 32 + dd * 4 + c] = s[dd][c];
        red[tc * 32 + 16 + dd * 4 + c] = q[dd][c];
      }
  }
  __syncthreads();
  if (!rg) {
#pragma unroll
    for (int dd = 0; dd < ND; ++dd)
#pragma unroll
      for (int c = 0; c < 4; ++c) {
        const float sv = s[dd][c] + red[tc * 32 + dd * 4 + c];
        const float qv = q[dd][c] + red[tc * 32 + 16 + dd * 4 + c];
        atomicAdd(&sums[dd * D + tc * 4 + c], sv);
        atomicAdd(&sqs[dd * D + tc * 4 + c], qv);
      }
  }
}

// ---------------------------------------------------------------------------
// Kernel C: finalize -> inv = gamma * rsqrt(var + eps), shift = beta - mean*inv.
// ---------------------------------------------------------------------------
__global__ __launch_bounds__(256) void fin_kernel(const float* __restrict__ sums,
                                                  const float* __restrict__ sqs,
                                                  const float* __restrict__ cnt,
                                                  const float* __restrict__ gamma,
                                                  const float* __restrict__ beta,
                                                  float* __restrict__ inv,
                                                  float* __restrict__ shf) {
  const int i = blockIdx.x * blockDim.x + threadIdx.x;
  if (i < ND * D) {
    const int d = i >> 9;  // /512
    const float c = fmaxf(cnt[d], 1.0f);
    const float m = sums[i] / c;
    const float va = sqs[i] / c - m * m;  // biased variance
    const float iv = gamma[i] * rsqrtf(va + EPSF);
    inv[i] = iv;
    shf[i] = beta[i] - m * iv;
  }
}

// ---------------------------------------------------------------------------
// Kernel D: out = fma(x, inv[dom], shift[dom]); float4, grid-stride row pairs.
// ---------------------------------------------------------------------------
__global__ __launch_bounds__(256) void norm_kernel(const float4* __restrict__ x,
                                                   const unsigned char* __restrict__ dom,
                                                   const float4* __restrict__ inv,
                                                   const float4* __restrict__ shf,
                                                   float4* __restrict__ out, int B) {
  const int t = threadIdx.x;
  const int tc = t & 127;
  const int rg = t >> 7;
  const int stride = gridDim.x * 2;
  for (int r = blockIdx.x * 2 + rg; r < B; r += stride) {
    const int d = dom[r];
    float4 v = x[(size_t)r * D4 + tc];
    float4 a = inv[d * D4 + tc];  // 16 KiB tables -> L1/L2 hits
    float4 b = shf[d * D4 + tc];
    float4 o;
    o.x = fmaf(v.x, a.x, b.x);
    o.y = fmaf(v.y, a.y, b.y);
    o.z = fmaf(v.z, a.z, b.z);
    o.w = fmaf(v.w, a.w, b.w);
    out[(size_t)r * D4 + tc] = o;
  }
}

extern "C" void kernel_launch(void* const* d_in, const int* in_sizes, int n_in,
                              void* d_out, int out_size, void* d_ws, size_t ws_size,
                              hipStream_t stream) {
  const float* x = (const float*)d_in[0];
  const float* ind = (const float*)d_in[1];
  const float* gamma = (const float*)d_in[2];
  const float* beta = (const float*)d_in[3];
  float* out = (float*)d_out;
  const int B = in_sizes[0] / D;

  // Workspace layout (bytes):
  //   [0,16)        cnt[ND]
  //   [256,8448)    sums[ND*D]
  //   [8448,16640)  sqs[ND*D]
  //   [16640,24832) inv[ND*D]
  //   [24832,33024) shf[ND*D]
  //   [33024,...)   dom[B] uint8
  char* ws = (char*)d_ws;
  float* cnt = (float*)(ws + 0);
  float* sums = (float*)(ws + 256);
  float* sqs = (float*)(ws + 256 + 8192);
  float* inv = (float*)(ws + 256 + 16384);
  float* shf = (float*)(ws + 256 + 24576);
  unsigned char* dom = (unsigned char*)(ws + 256 + 32768);

  // Accumulators must start at zero (ws is poisoned 0xAA before every call).
  (void)hipMemsetAsync(d_ws, 0, 256 + 16384, stream);

  dom_kernel<<<(B + 255) / 256, 256, 0, stream>>>((const float4*)ind, dom, cnt, B);

  const int NBLK = 512;
  const int rpb = ((B + NBLK * 2 - 1) / (NBLK * 2)) * 2;
  stats_kernel<<<NBLK, 256, 0, stream>>>((const float4*)x, dom, sums, sqs, B, rpb);

  fin_kernel<<<(ND * D + 255) / 256, 256, 0, stream>>>(sums, sqs, cnt, gamma, beta,
                                                       inv, shf);

  norm_kernel<<<2048, 256, 0, stream>>>((const float4*)x, dom, (const float4*)inv,
                                        (const float4*)shf, (float4*)out, B);
}